// Round 6
// baseline (618.391 us; speedup 1.0000x reference)
//
#include <hip/hip_runtime.h>
#include <hip/hip_bf16.h>

typedef unsigned int uint32;
typedef unsigned short ushort16;
typedef __attribute__((ext_vector_type(8))) __bf16 bf16x8;
typedef __attribute__((ext_vector_type(4))) float f32x4;

__device__ __forceinline__ ushort16 f2bf(float f) {
    uint32 u = __float_as_uint(f);
    u += 0x7fff + ((u >> 16) & 1);       // round-to-nearest-even
    return (ushort16)(u >> 16);
}
// pack two fp32 -> dword of 2 bf16 (a in low half)
__device__ __forceinline__ uint32 pack2rn(float a, float b) {
    uint32 ua = __float_as_uint(a) + 0x8000u;
    uint32 ub = __float_as_uint(b) + 0x8000u;
    return __builtin_amdgcn_perm(ub, ua, 0x07060302);  // [a.hi16, b.hi16]
}
__device__ __forceinline__ float blo(uint32 u) { return __uint_as_float(u << 16); }
__device__ __forceinline__ float bhi(uint32 u) { return __uint_as_float(u & 0xffff0000u); }

__device__ __forceinline__ void storeC(float v, float* p) { *p = v; }
__device__ __forceinline__ void storeC(float v, ushort16* p) { *p = f2bf(v); }

// async 16B global -> LDS (linear dest: wave-uniform base + lane*16)
__device__ __forceinline__ void gload_lds16(const void* g, void* l) {
    __builtin_amdgcn_global_load_lds(
        (const __attribute__((address_space(1))) unsigned int*)g,
        (__attribute__((address_space(3))) unsigned int*)l, 16, 0, 0);
}

// -log2(5000)/64 : rope inv-freq exponent step
#define ROPE_NEGSTEP (-0.19199550593046019f)

// ---------------------------------------------------------------------------
// Prep (one launch): blocks [0,8192) convert x,y fp32->bf16;
// blocks [8192,18432) transpose Wq/Wk/Wv/Wo [4096][N] fp32 -> [N][4096] bf16.
// ---------------------------------------------------------------------------
__global__ __launch_bounds__(256) void prep_kernel(
    const float* __restrict__ x, const float* __restrict__ y,
    const float* __restrict__ Wq, const float* __restrict__ Wk,
    const float* __restrict__ Wv, const float* __restrict__ Wo,
    ushort16* __restrict__ xb, ushort16* __restrict__ yb,
    ushort16* __restrict__ Wqt, ushort16* __restrict__ Wkvt,
    ushort16* __restrict__ Wot)
{
    __shared__ float tile[64][65];
    const int b = blockIdx.x;
    if (b < 8192) {                       // conv: 2*n8 threads, n8 = S*D/8
        const int n8 = 1048576;
        int idx = b * 256 + threadIdx.x;
        const float* S = (idx < n8) ? x : y;
        ushort16*    D = (idx < n8) ? xb : yb;
        int i = (idx < n8) ? idx : idx - n8;
        float4 a = ((const float4*)S)[2 * i];
        float4 c = ((const float4*)S)[2 * i + 1];
        uint4 u;
        u.x = pack2rn(a.x, a.y); u.y = pack2rn(a.z, a.w);
        u.z = pack2rn(c.x, c.y); u.w = pack2rn(c.z, c.w);
        ((uint4*)D)[i] = u;
        return;
    }
    int t = b - 8192;                     // 0..10239
    int kblk = t & 63, sel = t >> 6;      // sel 0..159
    const float* W; ushort16* Wt; int N, n0;
    if (sel < 64)      { W = Wq; Wt = Wqt;  N = 4096; n0 = sel * 64; }
    else if (sel < 80) { W = Wk; Wt = Wkvt; N = 1024; n0 = (sel - 64) * 64; }
    else if (sel < 96) { W = Wv; Wt = Wkvt + (size_t)1024 * 4096; N = 1024; n0 = (sel - 80) * 64; }
    else               { W = Wo; Wt = Wot;  N = 4096; n0 = (sel - 96) * 64; }
    const int k0 = kblk * 64;
#pragma unroll
    for (int it = 0; it < 16; ++it) {
        int idx = threadIdx.x + it * 256;
        int r = idx >> 6, c = idx & 63;
        tile[r][c] = W[(size_t)(k0 + r) * N + n0 + c];
    }
    __syncthreads();
#pragma unroll
    for (int it = 0; it < 8; ++it) {
        int idx = threadIdx.x + it * 256;
        int nr = idx >> 5, kp = idx & 31;
        uint32 u = pack2rn(tile[2 * kp][nr], tile[2 * kp + 1][nr]);
        *(uint32*)&Wt[(size_t)(n0 + nr) * 4096 + k0 + 2 * kp] = u;
    }
}

// ---------------------------------------------------------------------------
// Merged Q + KV GEMM with FUSED ROPE epilogues (grid 48 x 16).
//   x < 32 : Qb = rope(xb @ Wqt^T + bq) * sc  -> bf16 [2048][4096] (in d_out)
//   32<=x<40: K  = rope(yb @ Wk^T + bk)       -> bf16 KVb cols [0,1024)
//   x >= 40: V  = yb @ Wv^T + bv              -> bf16 KVb cols [1024,2048)
// Rope pairs (2i,2i+1) are adjacent lanes (col = ...+m16): one shfl_xor(v,1)
// rotates in-register; even lanes store packed u32 pairs.
// m97 staging: global_load_lds 16B, XOR swizzle folded into global src addr.
// ---------------------------------------------------------------------------
__global__ __launch_bounds__(256) void gemm_qkv(
    const ushort16* __restrict__ xb, const ushort16* __restrict__ yb,
    const ushort16* __restrict__ Wqt, const ushort16* __restrict__ Wkvt,
    const float* __restrict__ bq, const float* __restrict__ bk,
    const float* __restrict__ bv, ushort16* __restrict__ Qb,
    ushort16* __restrict__ KVb)
{
    __shared__ __align__(16) ushort16 As[128 * 64];
    __shared__ __align__(16) ushort16 Bs[128 * 64];

    const bool isQ = (blockIdx.x < 32);
    const ushort16* A = isQ ? xb : yb;
    const ushort16* B = isQ ? Wqt : Wkvt;
    const int gn0 = (isQ ? (int)blockIdx.x : (int)blockIdx.x - 32) * 128;
    const int gm0 = blockIdx.y * 128;
    const int K = 4096;

    const int tid  = threadIdx.x;
    const int lane = tid & 63, wave = tid >> 6;
    const int quad = lane >> 4, m16 = lane & 15;
    const int wm = (wave >> 1) * 64, wn = (wave & 1) * 64;

    f32x4 acc[4][4];
#pragma unroll
    for (int i = 0; i < 4; ++i)
#pragma unroll
        for (int j = 0; j < 4; ++j) acc[i][j] = (f32x4){0.f, 0.f, 0.f, 0.f};

    const int rl = lane >> 3, cl = lane & 7;
    const int clog = cl ^ (rl & 7);
    const ushort16* Ag = A + (size_t)(gm0 + wave * 32 + rl) * K + clog * 8;
    const ushort16* Bg = B + (size_t)(gn0 + wave * 32 + rl) * K + clog * 8;
    char* AsW = (char*)As + wave * 4096;
    char* BsW = (char*)Bs + wave * 4096;

    for (int k0 = 0; k0 < K; k0 += 64) {
        __syncthreads();
#pragma unroll
        for (int i = 0; i < 4; ++i) {
            gload_lds16(Ag + (size_t)(8 * i) * K, AsW + i * 1024);
            gload_lds16(Bg + (size_t)(8 * i) * K, BsW + i * 1024);
        }
        Ag += 64; Bg += 64;
        __syncthreads();

#pragma unroll
        for (int s = 0; s < 2; ++s) {
            bf16x8 aF[4], bF[4];
            const int cr = s * 4 + quad;
#pragma unroll
            for (int i = 0; i < 4; ++i) {
                int r = wm + i * 16 + m16;
                aF[i] = *(const bf16x8*)&As[r * 64 + ((cr ^ (r & 7)) * 8)];
                int n = wn + i * 16 + m16;
                bF[i] = *(const bf16x8*)&Bs[n * 64 + ((cr ^ (n & 7)) * 8)];
            }
            __builtin_amdgcn_s_setprio(1);
#pragma unroll
            for (int i = 0; i < 4; ++i)
#pragma unroll
                for (int j = 0; j < 4; ++j)
                    acc[i][j] = __builtin_amdgcn_mfma_f32_16x16x32_bf16(
                        aF[i], bF[j], acc[i][j], 0, 0, 0);
            __builtin_amdgcn_s_setprio(0);
        }
    }

    // ---- epilogues (block-uniform branch) --------------------------------
    if (isQ) {
        // rope + scale, bf16 pairs.  sc = 1/sqrt(128) * log2(e)
        const float sc = 0.08838834764831845f * 1.4426950408889634f;
#pragma unroll
        for (int j = 0; j < 4; ++j) {
            int col = gn0 + wn + j * 16 + m16;
            float bb = bq[col];
            int ip = (col & 127) >> 1;
            float inv = exp2f((float)ip * ROPE_NEGSTEP);
#pragma unroll
            for (int i = 0; i < 4; ++i) {
                int row0 = gm0 + wm + i * 16 + quad * 4;
#pragma unroll
                for (int r = 0; r < 4; ++r) {
                    int s = row0 + r;
                    float v = acc[i][j][r] + bb;
                    float pv = __shfl_xor(v, 1);
                    float ang = (float)s * inv;
                    float sn = __sinf(ang), cs = __cosf(ang);
                    float o = (lane & 1) ? (pv * sn + v * cs)
                                         : (v * cs - pv * sn);
                    o *= sc;
                    float po = __shfl_xor(o, 1);
                    if (!(lane & 1))
                        *(uint32*)&Qb[(size_t)s * 4096 + col] = pack2rn(o, po);
                }
            }
        }
    } else if (gn0 < 1024) {
        // K with rope, bf16 pairs into KVb cols [0,1024)
#pragma unroll
        for (int j = 0; j < 4; ++j) {
            int col = gn0 + wn + j * 16 + m16;
            float bb = bk[col];
            int ip = (col & 127) >> 1;
            float inv = exp2f((float)ip * ROPE_NEGSTEP);
#pragma unroll
            for (int i = 0; i < 4; ++i) {
                int row0 = gm0 + wm + i * 16 + quad * 4;
#pragma unroll
                for (int r = 0; r < 4; ++r) {
                    int s = row0 + r;
                    float v = acc[i][j][r] + bb;
                    float pv = __shfl_xor(v, 1);
                    float ang = (float)s * inv;
                    float sn = __sinf(ang), cs = __cosf(ang);
                    float o = (lane & 1) ? (pv * sn + v * cs)
                                         : (v * cs - pv * sn);
                    float po = __shfl_xor(o, 1);
                    if (!(lane & 1))
                        *(uint32*)&KVb[(size_t)s * 2048 + col] = pack2rn(o, po);
                }
            }
        }
    } else {
        // V plain, bf16 pairs into KVb cols [1024,2048)
#pragma unroll
        for (int j = 0; j < 4; ++j) {
            int col = gn0 + wn + j * 16 + m16;
            float bb = bv[col - 1024];
#pragma unroll
            for (int i = 0; i < 4; ++i) {
                int row0 = gm0 + wm + i * 16 + quad * 4;
#pragma unroll
                for (int r = 0; r < 4; ++r) {
                    float v = acc[i][j][r] + bb;
                    float pv = __shfl_xor(v, 1);
                    if (!(lane & 1))
                        *(uint32*)&KVb[(size_t)(row0 + r) * 2048 + col] = pack2rn(v, pv);
                }
            }
        }
    }
}

// ---------------------------------------------------------------------------
// MFMA GEMM (m97 structure): C = A[M,K] @ B[N,K]^T + bias (out projection).
// ---------------------------------------------------------------------------
template <typename OutT>
__global__ __launch_bounds__(256) void gemm_mfma(
    const ushort16* __restrict__ A, const ushort16* __restrict__ B,
    const float* __restrict__ b1, OutT* __restrict__ C, int N, int K)
{
    __shared__ __align__(16) ushort16 As[128 * 64];
    __shared__ __align__(16) ushort16 Bs[128 * 64];

    const int tid  = threadIdx.x;
    const int lane = tid & 63, wave = tid >> 6;
    const int quad = lane >> 4, m16 = lane & 15;
    const int wm = (wave >> 1) * 64, wn = (wave & 1) * 64;
    const int gm0 = blockIdx.y * 128, gn0 = blockIdx.x * 128;

    f32x4 acc[4][4];
#pragma unroll
    for (int i = 0; i < 4; ++i)
#pragma unroll
        for (int j = 0; j < 4; ++j) acc[i][j] = (f32x4){0.f, 0.f, 0.f, 0.f};

    const int rl = lane >> 3, cl = lane & 7;
    const int clog = cl ^ (rl & 7);
    const ushort16* Ag = A + (size_t)(gm0 + wave * 32 + rl) * K + clog * 8;
    const ushort16* Bg = B + (size_t)(gn0 + wave * 32 + rl) * K + clog * 8;
    char* AsW = (char*)As + wave * 4096;
    char* BsW = (char*)Bs + wave * 4096;

    for (int k0 = 0; k0 < K; k0 += 64) {
        __syncthreads();
#pragma unroll
        for (int i = 0; i < 4; ++i) {
            gload_lds16(Ag + (size_t)(8 * i) * K, AsW + i * 1024);
            gload_lds16(Bg + (size_t)(8 * i) * K, BsW + i * 1024);
        }
        Ag += 64; Bg += 64;
        __syncthreads();

#pragma unroll
        for (int s = 0; s < 2; ++s) {
            bf16x8 aF[4], bF[4];
            const int cr = s * 4 + quad;
#pragma unroll
            for (int i = 0; i < 4; ++i) {
                int r = wm + i * 16 + m16;
                aF[i] = *(const bf16x8*)&As[r * 64 + ((cr ^ (r & 7)) * 8)];
                int n = wn + i * 16 + m16;
                bF[i] = *(const bf16x8*)&Bs[n * 64 + ((cr ^ (n & 7)) * 8)];
            }
            __builtin_amdgcn_s_setprio(1);
#pragma unroll
            for (int i = 0; i < 4; ++i)
#pragma unroll
                for (int j = 0; j < 4; ++j)
                    acc[i][j] = __builtin_amdgcn_mfma_f32_16x16x32_bf16(
                        aF[i], bF[j], acc[i][j], 0, 0, 0);
            __builtin_amdgcn_s_setprio(0);
        }
    }

#pragma unroll
    for (int j = 0; j < 4; ++j) {
        int col = gn0 + wn + j * 16 + m16;
        float bb = b1[col];
#pragma unroll
        for (int i = 0; i < 4; ++i) {
            int row0 = gm0 + wm + i * 16 + quad * 4;
#pragma unroll
            for (int r = 0; r < 4; ++r)
                storeC(acc[i][j][r] + bb, C + (size_t)(row0 + r) * N + col);
        }
    }
}

// ---------------------------------------------------------------------------
// V transpose: KVb cols [1024,2048) -> Vt [1024][2048] bf16. 512 blocks.
// ---------------------------------------------------------------------------
__global__ __launch_bounds__(256) void vtrans_kernel(
    const ushort16* __restrict__ KVb, ushort16* __restrict__ Vt)
{
    __shared__ ushort16 tile[64][66];
    int t = blockIdx.x;
    int s0 = (t >> 4) * 64, d0 = (t & 15) * 64;
#pragma unroll
    for (int it = 0; it < 2; ++it) {
        int i = threadIdx.x + it * 256;    // 0..511
        int r = i >> 3, c = (i & 7) * 8;
        *(uint4*)&tile[r][c] = *(const uint4*)&KVb[(size_t)(s0 + r) * 2048 + 1024 + d0 + c];
    }
    __syncthreads();
#pragma unroll
    for (int it = 0; it < 2; ++it) {
        int i = threadIdx.x + it * 256;
        int dr = i >> 3, sc = (i & 7) * 8;
        uint32 w[4];
#pragma unroll
        for (int q = 0; q < 4; ++q)
            w[q] = (uint32)tile[sc + 2 * q][dr] | ((uint32)tile[sc + 2 * q + 1][dr] << 16);
        *(uint4*)&Vt[(size_t)(d0 + dr) * 2048 + s0 + sc] = *(uint4*)w;
    }
}

// ---------------------------------------------------------------------------
// MFMA flash attention (R5 structure: paired q-tiles, async dbuf K, DMA'd V
// from pre-transposed Vt, counted vmcnt before PV).  This round:
//  + defer-max (T13, THR=0): skip O-rescale when no row max grew (bitwise
//    identical output - skipped rescale would multiply by exp2(0)=1).
//  + Ps row stride 64 -> 72 elems (144B, 16B-aligned): quad rows no longer
//    alias to the same banks on P writes (SQ_LDS_BANK_CONFLICT fix).
// LDS: Kb 32K + Vs 16K + Ps 9.2K ~= 57.2 KB -> 2 blocks/CU.
// ---------------------------------------------------------------------------
__global__ __launch_bounds__(256) void flash_attn_kernel(
    const ushort16* __restrict__ Qb, const ushort16* __restrict__ KVb,
    const ushort16* __restrict__ Vtg, ushort16* __restrict__ O)
{
    __shared__ __align__(16) ushort16 Kb[2][64 * 128];  // [kv][d], swizzled
    __shared__ __align__(16) ushort16 Vs[128 * 64];     // [d][kv], swizzled
    __shared__ __align__(16) ushort16 Ps[64 * 72];      // [q][kv], stride 72

    const int tid  = threadIdx.x;
    const int lane = tid & 63, wave = tid >> 6;
    const int quad = lane >> 4, m16 = lane & 15;
    const int h = (int)blockIdx.y, kvh = h >> 2;

    const ushort16* Kbase = KVb + kvh * 128;
    const ushort16* Vbase = Vtg + (size_t)(kvh * 128) * 2048;

    const int rK = lane >> 4;
    const ushort16* pKe = Kbase + (size_t)(wave * 16 + rK) * 2048
                        + (((lane & 15) ^ rK) * 8);
    const ushort16* pKo = Kbase + (size_t)(wave * 16 + 4 + rK) * 2048
                        + (((lane & 15) ^ (4 + rK)) * 8);
    const int rV = lane >> 3;
    const ushort16* pV  = Vbase + (size_t)(wave * 32 + rV) * 2048
                        + (((lane & 7) ^ rV) * 8);
    char* ldsK0 = (char*)&Kb[0][0] + wave * 4096;
    char* ldsK1 = (char*)&Kb[1][0] + wave * 4096;
    char* ldsV  = (char*)&Vs[0]    + wave * 4096;

#define STAGE_K(dst, kk) do {                                   \
        const ushort16* _s0 = pKe + (size_t)(kk) * 2048;        \
        const ushort16* _s1 = pKo + (size_t)(kk) * 2048;        \
        gload_lds16(_s0,            (dst));                     \
        gload_lds16(_s1,            (dst) + 1024);              \
        gload_lds16(_s0 + 8 * 2048, (dst) + 2048);              \
        gload_lds16(_s1 + 8 * 2048, (dst) + 3072);              \
    } while (0)
#define STAGE_V(kk) do {                                        \
        const ushort16* _sv = pV + (kk);                        \
        gload_lds16(_sv,             ldsV);                     \
        gload_lds16(_sv +  8 * 2048, ldsV + 1024);              \
        gload_lds16(_sv + 16 * 2048, ldsV + 2048);              \
        gload_lds16(_sv + 24 * 2048, ldsV + 3072);              \
    } while (0)

    for (int pass = 0; pass < 2; ++pass) {
        const int qi = pass ? (int)blockIdx.x : 31 - (int)blockIdx.x;
        const int q0 = qi * 64;

        bf16x8 qa[4];
        {
            const ushort16* qp = Qb + (size_t)(q0 + wave * 16 + m16) * 4096
                               + h * 128 + quad * 8;
#pragma unroll
            for (int ks = 0; ks < 4; ++ks)
                qa[ks] = *(const bf16x8*)(qp + ks * 32);
        }

        f32x4 acc_o[8];
#pragma unroll
        for (int t = 0; t < 8; ++t) acc_o[t] = (f32x4){0.f, 0.f, 0.f, 0.f};
        float m_i[4], l_i[4];
#pragma unroll
        for (int r = 0; r < 4; ++r) { m_i[r] = -1e30f; l_i[r] = 0.f; }

        int cur = 0;
        STAGE_K(ldsK0, 0);

        for (int k0 = 0; k0 <= q0; k0 += 64) {
            __syncthreads();         // K(cur) landed; Vs reusable

            STAGE_V(k0);
            const bool pre = (k0 + 64 <= q0);
            if (pre) STAGE_K(cur ? ldsK0 : ldsK1, k0 + 64);

            const ushort16* Kcur = &Kb[cur][0];

            // S = Q @ K^T
            f32x4 sacc[4];
#pragma unroll
            for (int j = 0; j < 4; ++j) sacc[j] = (f32x4){0.f, 0.f, 0.f, 0.f};
            __builtin_amdgcn_s_setprio(1);
#pragma unroll
            for (int ks = 0; ks < 4; ++ks) {
#pragma unroll
                for (int j = 0; j < 4; ++j) {
                    int n = j * 16 + m16;
                    bf16x8 kb = *(const bf16x8*)&Kcur[n * 128 + (((ks * 4 + quad) ^ (n & 7)) * 8)];
                    sacc[j] = __builtin_amdgcn_mfma_f32_16x16x32_bf16(qa[ks], kb, sacc[j], 0, 0, 0);
                }
            }
            __builtin_amdgcn_s_setprio(0);

            if (k0 == q0) {   // causal mask on diagonal tile
                int qr = wave * 16 + quad * 4;
#pragma unroll
                for (int j = 0; j < 4; ++j) {
                    int kvl = j * 16 + m16;
#pragma unroll
                    for (int r = 0; r < 4; ++r)
                        if (kvl > qr + r) sacc[j][r] = -1e30f;
                }
            }

            // online softmax, exp2 domain, defer-max
            float rm[4];
#pragma unroll
            for (int r = 0; r < 4; ++r) {
                float v = fmaxf(fmaxf(sacc[0][r], sacc[1][r]), fmaxf(sacc[2][r], sacc[3][r]));
                v = fmaxf(v, __shfl_xor(v, 1));
                v = fmaxf(v, __shfl_xor(v, 2));
                v = fmaxf(v, __shfl_xor(v, 4));
                v = fmaxf(v, __shfl_xor(v, 8));
                rm[r] = v;
            }
            int ok = (rm[0] <= m_i[0]) & (rm[1] <= m_i[1]) &
                     (rm[2] <= m_i[2]) & (rm[3] <= m_i[3]);
            if (!__all(ok)) {    // some row's max grew: rescale (al=1 rows no-op)
#pragma unroll
                for (int r = 0; r < 4; ++r) {
                    float mnew = fmaxf(m_i[r], rm[r]);
                    float al = exp2f(m_i[r] - mnew);
                    l_i[r] *= al;
                    m_i[r] = mnew;
#pragma unroll
                    for (int t = 0; t < 8; ++t) acc_o[t][r] *= al;
                }
            }
#pragma unroll
            for (int r = 0; r < 4; ++r) {
                float rs = 0.f;
#pragma unroll
                for (int j = 0; j < 4; ++j) {
                    float pv = exp2f(sacc[j][r] - m_i[r]);
                    sacc[j][r] = pv;
                    rs += pv;
                }
                rs += __shfl_xor(rs, 1);
                rs += __shfl_xor(rs, 2);
                rs += __shfl_xor(rs, 4);
                rs += __shfl_xor(rs, 8);
                l_i[r] += rs;
                int q = wave * 16 + quad * 4 + r;
#pragma unroll
                for (int j = 0; j < 4; ++j) {      // P -> Ps (wave-private rows)
                    int kv = j * 16 + m16;
                    Ps[q * 72 + (((kv >> 3) ^ (q & 7)) * 8) + (kv & 7)] = f2bf(sacc[j][r]);
                }
            }

            // drain own V loads (counted: K prefetch spans the barrier)
            if (pre) { asm volatile("s_waitcnt vmcnt(4)" ::: "memory"); }
            else     { asm volatile("s_waitcnt vmcnt(0)" ::: "memory"); }
            __builtin_amdgcn_sched_barrier(0);
            __builtin_amdgcn_s_barrier();

            // O += P @ V
            int qrow = wave * 16 + m16;
#pragma unroll
            for (int ks2 = 0; ks2 < 2; ++ks2) {
                bf16x8 pa = *(const bf16x8*)&Ps[qrow * 72 + (((ks2 * 4 + quad) ^ (qrow & 7)) * 8)];
                __builtin_amdgcn_s_setprio(1);
#pragma unroll
                for (int t = 0; t < 8; ++t) {
                    int d = t * 16 + m16;
                    bf16x8 vb = *(const bf16x8*)&Vs[d * 64 + (((ks2 * 4 + quad) ^ (d & 7)) * 8)];
                    acc_o[t] = __builtin_amdgcn_mfma_f32_16x16x32_bf16(pa, vb, acc_o[t], 0, 0, 0);
                }
                __builtin_amdgcn_s_setprio(0);
            }
            cur ^= 1;
        }

        // epilogue: O = bf16(acc/l)
        ushort16* op = O + (size_t)(q0 + wave * 16 + quad * 4) * 4096 + h * 128 + m16;
#pragma unroll
        for (int r = 0; r < 4; ++r) {
            float inv = 1.0f / l_i[r];
#pragma unroll
            for (int t = 0; t < 8; ++t)
                op[(size_t)r * 4096 + t * 16] = f2bf(acc_o[t][r] * inv);
        }
    }
#undef STAGE_K
#undef STAGE_V
}

// ---------------------------------------------------------------------------
extern "C" void kernel_launch(void* const* d_in, const int* in_sizes, int n_in,
                              void* d_out, int out_size, void* d_ws, size_t ws_size,
                              hipStream_t stream)
{
    const float* x  = (const float*)d_in[0];
    const float* y  = (const float*)d_in[1];
    const float* Wq = (const float*)d_in[2];
    const float* bq = (const float*)d_in[3];
    const float* Wk = (const float*)d_in[4];
    const float* bk = (const float*)d_in[5];
    const float* Wv = (const float*)d_in[6];
    const float* bv = (const float*)d_in[7];
    const float* Wo = (const float*)d_in[8];
    const float* bo = (const float*)d_in[9];
    float* out = (float*)d_out;

    const size_t MB = 1024 * 1024;

    // workspace layout (124 MB):
    char* ws = (char*)d_ws;
    ushort16* xb   = (ushort16*)(ws);             // 16 MB
    ushort16* yb   = (ushort16*)(ws + 16 * MB);   // 16 MB, reused as Ao
    ushort16* Wqt  = (ushort16*)(ws + 32 * MB);   // 32 MB [4096][4096]
    ushort16* Wkvt = (ushort16*)(ws + 64 * MB);   // 16 MB [2048][4096]
    ushort16* Wot  = (ushort16*)(ws + 80 * MB);   // 32 MB [4096][4096]
    ushort16* KVb  = (ushort16*)(ws + 112 * MB);  //  8 MB [S][2048] = K|V
    ushort16* Vtg  = (ushort16*)(ws + 120 * MB);  //  4 MB [1024][2048] = V^T
    ushort16* Ao   = yb;                          // alias (yb dead after QKV)
    ushort16* Qb   = (ushort16*)out;              // bf16 Q in d_out (16 MB),
                                                  // dead before out-GEMM write

    prep_kernel<<<18432, 256, 0, stream>>>(x, y, Wq, Wk, Wv, Wo,
                                           xb, yb, Wqt, Wkvt, Wot);

    // Qb = rope(x@Wq+bq)*sc, KVb = [rope(y@Wk+bk) | y@Wv+bv], one launch
    gemm_qkv<<<dim3(48, 16), 256, 0, stream>>>(
        xb, yb, Wqt, Wkvt, bq, bk, bv, Qb, KVb);

    vtrans_kernel<<<512, 256, 0, stream>>>(KVb, Vtg);

    flash_attn_kernel<<<dim3(16, 32), 256, 0, stream>>>(Qb, KVb, Vtg, Ao);

    gemm_mfma<float><<<dim3(32, 16), 256, 0, stream>>>(
        Ao, Wot, bo, out, 4096, 4096);
}

// Round 7
// 567.887 us; speedup vs baseline: 1.0889x; 1.0889x over previous
//
#include <hip/hip_runtime.h>
#include <hip/hip_bf16.h>

typedef unsigned int uint32;
typedef unsigned short ushort16;
typedef __attribute__((ext_vector_type(8))) __bf16 bf16x8;
typedef __attribute__((ext_vector_type(4))) float f32x4;

__device__ __forceinline__ ushort16 f2bf(float f) {
    uint32 u = __float_as_uint(f);
    u += 0x7fff + ((u >> 16) & 1);       // round-to-nearest-even
    return (ushort16)(u >> 16);
}
// pack two fp32 -> dword of 2 bf16 (a in low half)
__device__ __forceinline__ uint32 pack2rn(float a, float b) {
    uint32 ua = __float_as_uint(a) + 0x8000u;
    uint32 ub = __float_as_uint(b) + 0x8000u;
    return __builtin_amdgcn_perm(ub, ua, 0x07060302);  // [a.hi16, b.hi16]
}
__device__ __forceinline__ float blo(uint32 u) { return __uint_as_float(u << 16); }
__device__ __forceinline__ float bhi(uint32 u) { return __uint_as_float(u & 0xffff0000u); }

__device__ __forceinline__ void storeC(float v, float* p) { *p = v; }
__device__ __forceinline__ void storeC(float v, ushort16* p) { *p = f2bf(v); }

// async 16B global -> LDS (linear dest: wave-uniform base + lane*16)
__device__ __forceinline__ void gload_lds16(const void* g, void* l) {
    __builtin_amdgcn_global_load_lds(
        (const __attribute__((address_space(1))) unsigned int*)g,
        (__attribute__((address_space(3))) unsigned int*)l, 16, 0, 0);
}

// -log2(5000)/64 : rope inv-freq exponent step
#define ROPE_NEGSTEP (-0.19199550593046019f)

// rope a fp32 pair (tr,ti) at pair-index ip, seq pos s; scale; pack to 2 bf16
__device__ __forceinline__ uint32 rope_pack(float tr, float ti, int ip, int s,
                                            float sc) {
    float inv = exp2f((float)ip * ROPE_NEGSTEP);
    float ang = (float)s * inv;
    float sn = __sinf(ang), cs = __cosf(ang);
    return pack2rn((tr * cs - ti * sn) * sc, (tr * sn + ti * cs) * sc);
}

// ---------------------------------------------------------------------------
// Prep (one launch): blocks [0,8192) convert x,y fp32->bf16;
// blocks [8192,18432) transpose Wq/Wk/Wv/Wo [4096][N] fp32 -> [N][4096] bf16.
// ---------------------------------------------------------------------------
__global__ __launch_bounds__(256) void prep_kernel(
    const float* __restrict__ x, const float* __restrict__ y,
    const float* __restrict__ Wq, const float* __restrict__ Wk,
    const float* __restrict__ Wv, const float* __restrict__ Wo,
    ushort16* __restrict__ xb, ushort16* __restrict__ yb,
    ushort16* __restrict__ Wqt, ushort16* __restrict__ Wkvt,
    ushort16* __restrict__ Wot)
{
    __shared__ float tile[64][65];
    const int b = blockIdx.x;
    if (b < 8192) {                       // conv: 2*n8 threads, n8 = S*D/8
        const int n8 = 1048576;
        int idx = b * 256 + threadIdx.x;
        const float* S = (idx < n8) ? x : y;
        ushort16*    D = (idx < n8) ? xb : yb;
        int i = (idx < n8) ? idx : idx - n8;
        float4 a = ((const float4*)S)[2 * i];
        float4 c = ((const float4*)S)[2 * i + 1];
        uint4 u;
        u.x = pack2rn(a.x, a.y); u.y = pack2rn(a.z, a.w);
        u.z = pack2rn(c.x, c.y); u.w = pack2rn(c.z, c.w);
        ((uint4*)D)[i] = u;
        return;
    }
    int t = b - 8192;                     // 0..10239
    int kblk = t & 63, sel = t >> 6;      // sel 0..159
    const float* W; ushort16* Wt; int N, n0;
    if (sel < 64)      { W = Wq; Wt = Wqt;  N = 4096; n0 = sel * 64; }
    else if (sel < 80) { W = Wk; Wt = Wkvt; N = 1024; n0 = (sel - 64) * 64; }
    else if (sel < 96) { W = Wv; Wt = Wkvt + (size_t)1024 * 4096; N = 1024; n0 = (sel - 80) * 64; }
    else               { W = Wo; Wt = Wot;  N = 4096; n0 = (sel - 96) * 64; }
    const int k0 = kblk * 64;
#pragma unroll
    for (int it = 0; it < 16; ++it) {
        int idx = threadIdx.x + it * 256;
        int r = idx >> 6, c = idx & 63;
        tile[r][c] = W[(size_t)(k0 + r) * N + n0 + c];
    }
    __syncthreads();
#pragma unroll
    for (int it = 0; it < 8; ++it) {
        int idx = threadIdx.x + it * 256;
        int nr = idx >> 5, kp = idx & 31;
        uint32 u = pack2rn(tile[2 * kp][nr], tile[2 * kp + 1][nr]);
        *(uint32*)&Wt[(size_t)(n0 + nr) * 4096 + k0 + 2 * kp] = u;
    }
}

// ---------------------------------------------------------------------------
// Merged Q + KV GEMM (grid 48 x 16), m97 structure, PLAIN epilogue (the
// measured-fast one: R5 bench 127us; the fused-rope epilogue cost +70us).
//   x < 32 : Q  = xb @ Wqt^T + bq  -> fp32 Q [2048][4096] (in d_out)
//   x >= 32: KV = yb @ Wkvt^T + bk|bv -> bf16 KVb [2048][2048]
// ---------------------------------------------------------------------------
__global__ __launch_bounds__(256) void gemm_qkv(
    const ushort16* __restrict__ xb, const ushort16* __restrict__ yb,
    const ushort16* __restrict__ Wqt, const ushort16* __restrict__ Wkvt,
    const float* __restrict__ bq, const float* __restrict__ bk,
    const float* __restrict__ bv, float* __restrict__ Q,
    ushort16* __restrict__ KVb)
{
    __shared__ __align__(16) ushort16 As[128 * 64];
    __shared__ __align__(16) ushort16 Bs[128 * 64];

    const bool isQ = (blockIdx.x < 32);
    const ushort16* A = isQ ? xb : yb;
    const ushort16* B = isQ ? Wqt : Wkvt;
    const int gn0 = (isQ ? (int)blockIdx.x : (int)blockIdx.x - 32) * 128;
    const int gm0 = blockIdx.y * 128;
    const int K = 4096;

    const int tid  = threadIdx.x;
    const int lane = tid & 63, wave = tid >> 6;
    const int quad = lane >> 4, m16 = lane & 15;
    const int wm = (wave >> 1) * 64, wn = (wave & 1) * 64;

    f32x4 acc[4][4];
#pragma unroll
    for (int i = 0; i < 4; ++i)
#pragma unroll
        for (int j = 0; j < 4; ++j) acc[i][j] = (f32x4){0.f, 0.f, 0.f, 0.f};

    const int rl = lane >> 3, cl = lane & 7;
    const int clog = cl ^ (rl & 7);
    const ushort16* Ag = A + (size_t)(gm0 + wave * 32 + rl) * K + clog * 8;
    const ushort16* Bg = B + (size_t)(gn0 + wave * 32 + rl) * K + clog * 8;
    char* AsW = (char*)As + wave * 4096;
    char* BsW = (char*)Bs + wave * 4096;

    for (int k0 = 0; k0 < K; k0 += 64) {
        __syncthreads();
#pragma unroll
        for (int i = 0; i < 4; ++i) {
            gload_lds16(Ag + (size_t)(8 * i) * K, AsW + i * 1024);
            gload_lds16(Bg + (size_t)(8 * i) * K, BsW + i * 1024);
        }
        Ag += 64; Bg += 64;
        __syncthreads();

#pragma unroll
        for (int s = 0; s < 2; ++s) {
            bf16x8 aF[4], bF[4];
            const int cr = s * 4 + quad;
#pragma unroll
            for (int i = 0; i < 4; ++i) {
                int r = wm + i * 16 + m16;
                aF[i] = *(const bf16x8*)&As[r * 64 + ((cr ^ (r & 7)) * 8)];
                int n = wn + i * 16 + m16;
                bF[i] = *(const bf16x8*)&Bs[n * 64 + ((cr ^ (n & 7)) * 8)];
            }
            __builtin_amdgcn_s_setprio(1);
#pragma unroll
            for (int i = 0; i < 4; ++i)
#pragma unroll
                for (int j = 0; j < 4; ++j)
                    acc[i][j] = __builtin_amdgcn_mfma_f32_16x16x32_bf16(
                        aF[i], bF[j], acc[i][j], 0, 0, 0);
            __builtin_amdgcn_s_setprio(0);
        }
    }

#pragma unroll
    for (int j = 0; j < 4; ++j) {
        int col = gn0 + wn + j * 16 + m16;
        float bb = isQ ? bq[col] : ((col < 1024) ? bk[col] : bv[col - 1024]);
#pragma unroll
        for (int i = 0; i < 4; ++i) {
            int row0 = gm0 + wm + i * 16 + quad * 4;
#pragma unroll
            for (int r = 0; r < 4; ++r) {
                float v = acc[i][j][r] + bb;
                if (isQ) Q[(size_t)(row0 + r) * 4096 + col] = v;
                else     KVb[(size_t)(row0 + r) * 2048 + col] = f2bf(v);
            }
        }
    }
}

// ---------------------------------------------------------------------------
// MFMA GEMM (m97 structure): C = A[M,K] @ B[N,K]^T + bias (out projection).
// ---------------------------------------------------------------------------
template <typename OutT>
__global__ __launch_bounds__(256) void gemm_mfma(
    const ushort16* __restrict__ A, const ushort16* __restrict__ B,
    const float* __restrict__ b1, OutT* __restrict__ C, int N, int K)
{
    __shared__ __align__(16) ushort16 As[128 * 64];
    __shared__ __align__(16) ushort16 Bs[128 * 64];

    const int tid  = threadIdx.x;
    const int lane = tid & 63, wave = tid >> 6;
    const int quad = lane >> 4, m16 = lane & 15;
    const int wm = (wave >> 1) * 64, wn = (wave & 1) * 64;
    const int gm0 = blockIdx.y * 128, gn0 = blockIdx.x * 128;

    f32x4 acc[4][4];
#pragma unroll
    for (int i = 0; i < 4; ++i)
#pragma unroll
        for (int j = 0; j < 4; ++j) acc[i][j] = (f32x4){0.f, 0.f, 0.f, 0.f};

    const int rl = lane >> 3, cl = lane & 7;
    const int clog = cl ^ (rl & 7);
    const ushort16* Ag = A + (size_t)(gm0 + wave * 32 + rl) * K + clog * 8;
    const ushort16* Bg = B + (size_t)(gn0 + wave * 32 + rl) * K + clog * 8;
    char* AsW = (char*)As + wave * 4096;
    char* BsW = (char*)Bs + wave * 4096;

    for (int k0 = 0; k0 < K; k0 += 64) {
        __syncthreads();
#pragma unroll
        for (int i = 0; i < 4; ++i) {
            gload_lds16(Ag + (size_t)(8 * i) * K, AsW + i * 1024);
            gload_lds16(Bg + (size_t)(8 * i) * K, BsW + i * 1024);
        }
        Ag += 64; Bg += 64;
        __syncthreads();

#pragma unroll
        for (int s = 0; s < 2; ++s) {
            bf16x8 aF[4], bF[4];
            const int cr = s * 4 + quad;
#pragma unroll
            for (int i = 0; i < 4; ++i) {
                int r = wm + i * 16 + m16;
                aF[i] = *(const bf16x8*)&As[r * 64 + ((cr ^ (r & 7)) * 8)];
                int n = wn + i * 16 + m16;
                bF[i] = *(const bf16x8*)&Bs[n * 64 + ((cr ^ (n & 7)) * 8)];
            }
            __builtin_amdgcn_s_setprio(1);
#pragma unroll
            for (int i = 0; i < 4; ++i)
#pragma unroll
                for (int j = 0; j < 4; ++j)
                    acc[i][j] = __builtin_amdgcn_mfma_f32_16x16x32_bf16(
                        aF[i], bF[j], acc[i][j], 0, 0, 0);
            __builtin_amdgcn_s_setprio(0);
        }
    }

#pragma unroll
    for (int j = 0; j < 4; ++j) {
        int col = gn0 + wn + j * 16 + m16;
        float bb = b1[col];
#pragma unroll
        for (int i = 0; i < 4; ++i) {
            int row0 = gm0 + wm + i * 16 + quad * 4;
#pragma unroll
            for (int r = 0; r < 4; ++r)
                storeC(acc[i][j][r] + bb, C + (size_t)(row0 + r) * N + col);
        }
    }
}

// ---------------------------------------------------------------------------
// Merged rope-K + V-transpose (one small launch):
//  blocks [0,4096): rope bf16 K in-place (KVb cols [0,1024))
//  blocks [4096,4608): transpose V (KVb cols [1024,2048)) -> Vt[1024][2048]
// ---------------------------------------------------------------------------
__global__ __launch_bounds__(256) void ropek_vt_kernel(
    ushort16* __restrict__ KVb, ushort16* __restrict__ Vt)
{
    __shared__ ushort16 tile[64][66];
    const int b = blockIdx.x;
    if (b < 4096) {                        // rope K in place
        int idx = b * 256 + threadIdx.x;
        int i   = idx & 63;
        int rem = idx >> 6;                // s*8 + h
        int s   = rem >> 3, h = rem & 7;
        float inv = exp2f((float)i * ROPE_NEGSTEP);
        float ang = (float)s * inv;
        float cs = __cosf(ang), sn = __sinf(ang);
        uint32* p = (uint32*)&KVb[(size_t)s * 2048 + h * 128 + 2 * i];
        uint32 u = *p;
        float tr = blo(u), ti = bhi(u);
        *p = pack2rn(tr * cs - ti * sn, tr * sn + ti * cs);
        return;
    }
    // V^T 64x64 tile
    int t = b - 4096;
    int s0 = (t >> 4) * 64, d0 = (t & 15) * 64;
#pragma unroll
    for (int it = 0; it < 2; ++it) {
        int i = threadIdx.x + it * 256;    // 0..511
        int r = i >> 3, c = (i & 7) * 8;
        *(uint4*)&tile[r][c] = *(const uint4*)&KVb[(size_t)(s0 + r) * 2048 + 1024 + d0 + c];
    }
    __syncthreads();
#pragma unroll
    for (int it = 0; it < 2; ++it) {
        int i = threadIdx.x + it * 256;
        int dr = i >> 3, sc = (i & 7) * 8;
        uint32 w[4];
#pragma unroll
        for (int q = 0; q < 4; ++q)
            w[q] = (uint32)tile[sc + 2 * q][dr] | ((uint32)tile[sc + 2 * q + 1][dr] << 16);
        *(uint4*)&Vt[(size_t)(d0 + dr) * 2048 + s0 + sc] = *(uint4*)w;
    }
}

// ---------------------------------------------------------------------------
// MFMA flash attention (paired q-tiles, async dbuf K, DMA'd V from Vt,
// counted vmcnt before PV, defer-max, Ps stride 72).  This round: Q read as
// fp32 directly from the GEMM output; rope+scale applied IN-REGISTER at
// fragment-load time (each thread's 8 consecutive d-elements = 4 complete
// rope pairs; no shuffles, 16 sincos per pass - the rope-Q kernel, its 16MB
// Qb intermediate write AND its read disappear).
// LDS: Kb 32K + Vs 16K + Ps 9.2K ~= 57.2 KB -> 2 blocks/CU.
// ---------------------------------------------------------------------------
__global__ __launch_bounds__(256) void flash_attn_kernel(
    const float* __restrict__ Qf, const ushort16* __restrict__ KVb,
    const ushort16* __restrict__ Vtg, ushort16* __restrict__ O)
{
    __shared__ __align__(16) ushort16 Kb[2][64 * 128];  // [kv][d], swizzled
    __shared__ __align__(16) ushort16 Vs[128 * 64];     // [d][kv], swizzled
    __shared__ __align__(16) ushort16 Ps[64 * 72];      // [q][kv], stride 72

    const int tid  = threadIdx.x;
    const int lane = tid & 63, wave = tid >> 6;
    const int quad = lane >> 4, m16 = lane & 15;
    const int h = (int)blockIdx.y, kvh = h >> 2;

    const ushort16* Kbase = KVb + kvh * 128;
    const ushort16* Vbase = Vtg + (size_t)(kvh * 128) * 2048;

    const int rK = lane >> 4;
    const ushort16* pKe = Kbase + (size_t)(wave * 16 + rK) * 2048
                        + (((lane & 15) ^ rK) * 8);
    const ushort16* pKo = Kbase + (size_t)(wave * 16 + 4 + rK) * 2048
                        + (((lane & 15) ^ (4 + rK)) * 8);
    const int rV = lane >> 3;
    const ushort16* pV  = Vbase + (size_t)(wave * 32 + rV) * 2048
                        + (((lane & 7) ^ rV) * 8);
    char* ldsK0 = (char*)&Kb[0][0] + wave * 4096;
    char* ldsK1 = (char*)&Kb[1][0] + wave * 4096;
    char* ldsV  = (char*)&Vs[0]    + wave * 4096;

#define STAGE_K(dst, kk) do {                                   \
        const ushort16* _s0 = pKe + (size_t)(kk) * 2048;        \
        const ushort16* _s1 = pKo + (size_t)(kk) * 2048;        \
        gload_lds16(_s0,            (dst));                     \
        gload_lds16(_s1,            (dst) + 1024);              \
        gload_lds16(_s0 + 8 * 2048, (dst) + 2048);              \
        gload_lds16(_s1 + 8 * 2048, (dst) + 3072);              \
    } while (0)
#define STAGE_V(kk) do {                                        \
        const ushort16* _sv = pV + (kk);                        \
        gload_lds16(_sv,             ldsV);                     \
        gload_lds16(_sv +  8 * 2048, ldsV + 1024);              \
        gload_lds16(_sv + 16 * 2048, ldsV + 2048);              \
        gload_lds16(_sv + 24 * 2048, ldsV + 3072);              \
    } while (0)

    for (int pass = 0; pass < 2; ++pass) {
        const int qi = pass ? (int)blockIdx.x : 31 - (int)blockIdx.x;
        const int q0 = qi * 64;
        const int srow = q0 + wave * 16 + m16;      // this lane's seq position

        // Q A-fragments from fp32 + in-register rope + scale -> bf16
        const float sc = 0.08838834764831845f * 1.4426950408889634f;
        bf16x8 qa[4];
        {
            const float* qp = Qf + (size_t)srow * 4096 + h * 128 + quad * 8;
#pragma unroll
            for (int ks = 0; ks < 4; ++ks) {
                float4 a = *(const float4*)(qp + ks * 32);
                float4 b = *(const float4*)(qp + ks * 32 + 4);
                int ip0 = quad * 4 + ks * 16;       // pair idx of (a.x,a.y)
                uint4 u;
                u.x = rope_pack(a.x, a.y, ip0 + 0, srow, sc);
                u.y = rope_pack(a.z, a.w, ip0 + 1, srow, sc);
                u.z = rope_pack(b.x, b.y, ip0 + 2, srow, sc);
                u.w = rope_pack(b.z, b.w, ip0 + 3, srow, sc);
                qa[ks] = *(bf16x8*)&u;
            }
        }

        f32x4 acc_o[8];
#pragma unroll
        for (int t = 0; t < 8; ++t) acc_o[t] = (f32x4){0.f, 0.f, 0.f, 0.f};
        float m_i[4], l_i[4];
#pragma unroll
        for (int r = 0; r < 4; ++r) { m_i[r] = -1e30f; l_i[r] = 0.f; }

        int cur = 0;
        STAGE_K(ldsK0, 0);

        for (int k0 = 0; k0 <= q0; k0 += 64) {
            __syncthreads();         // K(cur) landed; Vs reusable

            STAGE_V(k0);
            const bool pre = (k0 + 64 <= q0);
            if (pre) STAGE_K(cur ? ldsK0 : ldsK1, k0 + 64);

            const ushort16* Kcur = &Kb[cur][0];

            // S = Q @ K^T
            f32x4 sacc[4];
#pragma unroll
            for (int j = 0; j < 4; ++j) sacc[j] = (f32x4){0.f, 0.f, 0.f, 0.f};
            __builtin_amdgcn_s_setprio(1);
#pragma unroll
            for (int ks = 0; ks < 4; ++ks) {
#pragma unroll
                for (int j = 0; j < 4; ++j) {
                    int n = j * 16 + m16;
                    bf16x8 kb = *(const bf16x8*)&Kcur[n * 128 + (((ks * 4 + quad) ^ (n & 7)) * 8)];
                    sacc[j] = __builtin_amdgcn_mfma_f32_16x16x32_bf16(qa[ks], kb, sacc[j], 0, 0, 0);
                }
            }
            __builtin_amdgcn_s_setprio(0);

            if (k0 == q0) {   // causal mask on diagonal tile
                int qr = wave * 16 + quad * 4;
#pragma unroll
                for (int j = 0; j < 4; ++j) {
                    int kvl = j * 16 + m16;
#pragma unroll
                    for (int r = 0; r < 4; ++r)
                        if (kvl > qr + r) sacc[j][r] = -1e30f;
                }
            }

            // online softmax, exp2 domain, defer-max (bitwise-safe, THR=0)
            float rm[4];
#pragma unroll
            for (int r = 0; r < 4; ++r) {
                float v = fmaxf(fmaxf(sacc[0][r], sacc[1][r]), fmaxf(sacc[2][r], sacc[3][r]));
                v = fmaxf(v, __shfl_xor(v, 1));
                v = fmaxf(v, __shfl_xor(v, 2));
                v = fmaxf(v, __shfl_xor(v, 4));
                v = fmaxf(v, __shfl_xor(v, 8));
                rm[r] = v;
            }
            int ok = (rm[0] <= m_i[0]) & (rm[1] <= m_i[1]) &
                     (rm[2] <= m_i[2]) & (rm[3] <= m_i[3]);
            if (!__all(ok)) {    // some row's max grew: rescale
#pragma unroll
                for (int r = 0; r < 4; ++r) {
                    float mnew = fmaxf(m_i[r], rm[r]);
                    float al = exp2f(m_i[r] - mnew);
                    l_i[r] *= al;
                    m_i[r] = mnew;
#pragma unroll
                    for (int t = 0; t < 8; ++t) acc_o[t][r] *= al;
                }
            }
#pragma unroll
            for (int r = 0; r < 4; ++r) {
                float rs = 0.f;
#pragma unroll
                for (int j = 0; j < 4; ++j) {
                    float pv = exp2f(sacc[j][r] - m_i[r]);
                    sacc[j][r] = pv;
                    rs += pv;
                }
                rs += __shfl_xor(rs, 1);
                rs += __shfl_xor(rs, 2);
                rs += __shfl_xor(rs, 4);
                rs += __shfl_xor(rs, 8);
                l_i[r] += rs;
                int q = wave * 16 + quad * 4 + r;
#pragma unroll
                for (int j = 0; j < 4; ++j) {      // P -> Ps (wave-private rows)
                    int kv = j * 16 + m16;
                    Ps[q * 72 + (((kv >> 3) ^ (q & 7)) * 8) + (kv & 7)] = f2bf(sacc[j][r]);
                }
            }

            // drain own V loads (counted: K prefetch spans the barrier)
            if (pre) { asm volatile("s_waitcnt vmcnt(4)" ::: "memory"); }
            else     { asm volatile("s_waitcnt vmcnt(0)" ::: "memory"); }
            __builtin_amdgcn_sched_barrier(0);
            __builtin_amdgcn_s_barrier();

            // O += P @ V
            int qrow = wave * 16 + m16;
#pragma unroll
            for (int ks2 = 0; ks2 < 2; ++ks2) {
                bf16x8 pa = *(const bf16x8*)&Ps[qrow * 72 + (((ks2 * 4 + quad) ^ (qrow & 7)) * 8)];
                __builtin_amdgcn_s_setprio(1);
#pragma unroll
                for (int t = 0; t < 8; ++t) {
                    int d = t * 16 + m16;
                    bf16x8 vb = *(const bf16x8*)&Vs[d * 64 + (((ks2 * 4 + quad) ^ (d & 7)) * 8)];
                    acc_o[t] = __builtin_amdgcn_mfma_f32_16x16x32_bf16(pa, vb, acc_o[t], 0, 0, 0);
                }
                __builtin_amdgcn_s_setprio(0);
            }
            cur ^= 1;
        }

        // epilogue: O = bf16(acc/l)
        ushort16* op = O + (size_t)(q0 + wave * 16 + quad * 4) * 4096 + h * 128 + m16;
#pragma unroll
        for (int r = 0; r < 4; ++r) {
            float inv = 1.0f / l_i[r];
#pragma unroll
            for (int t = 0; t < 8; ++t)
                op[(size_t)r * 4096 + t * 16] = f2bf(acc_o[t][r] * inv);
        }
    }
#undef STAGE_K
#undef STAGE_V
}

// ---------------------------------------------------------------------------
extern "C" void kernel_launch(void* const* d_in, const int* in_sizes, int n_in,
                              void* d_out, int out_size, void* d_ws, size_t ws_size,
                              hipStream_t stream)
{
    const float* x  = (const float*)d_in[0];
    const float* y  = (const float*)d_in[1];
    const float* Wq = (const float*)d_in[2];
    const float* bq = (const float*)d_in[3];
    const float* Wk = (const float*)d_in[4];
    const float* bk = (const float*)d_in[5];
    const float* Wv = (const float*)d_in[6];
    const float* bv = (const float*)d_in[7];
    const float* Wo = (const float*)d_in[8];
    const float* bo = (const float*)d_in[9];
    float* out = (float*)d_out;

    const size_t MB = 1024 * 1024;

    // workspace layout (124 MB):
    char* ws = (char*)d_ws;
    ushort16* xb   = (ushort16*)(ws);             // 16 MB
    ushort16* yb   = (ushort16*)(ws + 16 * MB);   // 16 MB, reused as Ao
    ushort16* Wqt  = (ushort16*)(ws + 32 * MB);   // 32 MB [4096][4096]
    ushort16* Wkvt = (ushort16*)(ws + 64 * MB);   // 16 MB [2048][4096]
    ushort16* Wot  = (ushort16*)(ws + 80 * MB);   // 32 MB [4096][4096]
    ushort16* KVb  = (ushort16*)(ws + 112 * MB);  //  8 MB [S][2048] = K|V
    ushort16* Vtg  = (ushort16*)(ws + 120 * MB);  //  4 MB [1024][2048] = V^T
    ushort16* Ao   = yb;                          // alias (yb dead after QKV)
    float*    Q    = out;                         // fp32 Q in d_out (32 MB),
                                                  // dead before out-GEMM write

    prep_kernel<<<18432, 256, 0, stream>>>(x, y, Wq, Wk, Wv, Wo,
                                           xb, yb, Wqt, Wkvt, Wot);

    // Q = x@Wq+bq (fp32), KV = y@[Wk|Wv]+[bk|bv] (bf16), one launch
    gemm_qkv<<<dim3(48, 16), 256, 0, stream>>>(
        xb, yb, Wqt, Wkvt, bq, bk, bv, Q, KVb);

    // rope K in place + V -> V^T
    ropek_vt_kernel<<<4608, 256, 0, stream>>>(KVb, Vtg);

    // flash reads fp32 Q and ropes in-register at fragment load
    flash_attn_kernel<<<dim3(16, 32), 256, 0, stream>>>(Q, KVb, Vtg, Ao);

    gemm_mfma<float><<<dim3(32, 16), 256, 0, stream>>>(
        Ao, Wot, bo, out, 4096, 4096);
}